// Round 4
// baseline (389.976 us; speedup 1.0000x reference)
//
#include <hip/hip_runtime.h>

typedef unsigned short u16;
typedef __attribute__((ext_vector_type(8))) short bf16x8;   // 8 bf16 = 4 VGPRs
typedef __attribute__((ext_vector_type(4))) float f32x4;

#define BM 256
#define BN 256
#define BKT 64

__device__ __forceinline__ void gload16(const void* g, void* l) {
  __builtin_amdgcn_global_load_lds(
      (const __attribute__((address_space(1))) unsigned int*)g,
      (__attribute__((address_space(3))) unsigned int*)l, 16, 0, 0);
}

// ---------------- per-row fake-quant, single-pass (K==4096) ----------------
__global__ __launch_bounds__(256) void quant_rows4096_kernel(
    const float* __restrict__ src, u16* __restrict__ q,
    float* __restrict__ scales)
{
  const size_t row = blockIdx.x;
  const float4* __restrict__ p = (const float4*)(src + row * 4096);
  const int t = threadIdx.x;
  float4 v0 = p[t];
  float4 v1 = p[t + 256];
  float4 v2 = p[t + 512];
  float4 v3 = p[t + 768];
  float m = 0.0f;
  m = fmaxf(m, fmaxf(fmaxf(fabsf(v0.x), fabsf(v0.y)), fmaxf(fabsf(v0.z), fabsf(v0.w))));
  m = fmaxf(m, fmaxf(fmaxf(fabsf(v1.x), fabsf(v1.y)), fmaxf(fabsf(v1.z), fabsf(v1.w))));
  m = fmaxf(m, fmaxf(fmaxf(fabsf(v2.x), fabsf(v2.y)), fmaxf(fabsf(v2.z), fabsf(v2.w))));
  m = fmaxf(m, fmaxf(fmaxf(fabsf(v3.x), fabsf(v3.y)), fmaxf(fabsf(v3.z), fabsf(v3.w))));
  #pragma unroll
  for (int off = 32; off > 0; off >>= 1) m = fmaxf(m, __shfl_xor(m, off));
  __shared__ float wmax[4];
  if ((t & 63) == 0) wmax[t >> 6] = m;
  __syncthreads();
  m = fmaxf(fmaxf(wmax[0], wmax[1]), fmaxf(wmax[2], wmax[3]));
  const float scale = fmaxf(m, 1e-5f) * (1.0f / 127.0f);
  if (t == 0) scales[row] = scale;
  ushort4* __restrict__ qp = (ushort4*)(q + row * 4096);
  #define QV(V, IDX) do { ushort4 o_; \
    o_.x = (u16)(__float_as_uint(rintf((V).x / scale)) >> 16); \
    o_.y = (u16)(__float_as_uint(rintf((V).y / scale)) >> 16); \
    o_.z = (u16)(__float_as_uint(rintf((V).z / scale)) >> 16); \
    o_.w = (u16)(__float_as_uint(rintf((V).w / scale)) >> 16); \
    qp[IDX] = o_; } while (0)
  QV(v0, t); QV(v1, t + 256); QV(v2, t + 512); QV(v3, t + 768);
  #undef QV
}

// generic fallback (any K multiple of 4)
__global__ __launch_bounds__(256) void quant_rows_kernel(
    const float* __restrict__ src, u16* __restrict__ q,
    float* __restrict__ scales, int K)
{
  const size_t row = blockIdx.x;
  const float* __restrict__ p = src + row * (size_t)K;
  const int t = threadIdx.x;
  const int nv = K >> 2;
  float m = 0.0f;
  for (int i = t; i < nv; i += 256) {
    float4 v = ((const float4*)p)[i];
    m = fmaxf(m, fmaxf(fmaxf(fabsf(v.x), fabsf(v.y)),
                       fmaxf(fabsf(v.z), fabsf(v.w))));
  }
  #pragma unroll
  for (int off = 32; off > 0; off >>= 1) m = fmaxf(m, __shfl_xor(m, off));
  __shared__ float wmax[4];
  if ((t & 63) == 0) wmax[t >> 6] = m;
  __syncthreads();
  m = fmaxf(fmaxf(wmax[0], wmax[1]), fmaxf(wmax[2], wmax[3]));
  const float scale = fmaxf(m, 1e-5f) * (1.0f / 127.0f);
  if (t == 0) scales[row] = scale;
  u16* __restrict__ qp = q + row * (size_t)K;
  for (int i = t; i < nv; i += 256) {
    float4 v = ((const float4*)p)[i];
    ushort4 o;
    o.x = (u16)(__float_as_uint(rintf(v.x / scale)) >> 16);
    o.y = (u16)(__float_as_uint(rintf(v.y / scale)) >> 16);
    o.z = (u16)(__float_as_uint(rintf(v.z / scale)) >> 16);
    o.w = (u16)(__float_as_uint(rintf(v.w / scale)) >> 16);
    ((ushort4*)qp)[i] = o;
  }
}

// ------- 256x256 8-wave GEMM, 4 regions/K-tile, reads pipelined & guaranteed -------
// C = Aq(MxK) * Bq(NxK)^T. LDS: 2 slots x (A 256x64 + B 256x64) bf16 = 128 KiB.
// Swizzle: LDS (row, slot16) holds global (row, slot16 ^ (row&7)).
// INVARIANT: every first ds_read of staged data sits AFTER a barrier preceded
// (in all waves) by a vmcnt drain covering that data. Cluster order:
// c1=(mh0,kk0) c2=(mh0,kk1) c3=(mh1,kk0) c4=(mh1,kk1).
__global__ __launch_bounds__(512, 2) void gemm_bt_kernel(
    const u16* __restrict__ Aq, const u16* __restrict__ Bq,
    const float* __restrict__ sx, const float* __restrict__ sw,
    const float* __restrict__ bias, float* __restrict__ Y,
    unsigned int* __restrict__ rowmax, int M, int N, int K)
{
  __shared__ u16 lds[2][2][BM * BKT];   // [slot][A/B]

  int bid = (int)blockIdx.x;
  const int nwg = (int)gridDim.x;
  if ((nwg & 7) == 0) {                 // bijective XCD swizzle
    const int cpx = nwg >> 3;
    bid = (bid & 7) * cpx + (bid >> 3);
  }
  const int ntile = N / BN;
  const size_t brow = (size_t)(bid / ntile) * BM;
  const size_t bcol = (size_t)(bid % ntile) * BN;

  const int t = threadIdx.x;
  const int lane = t & 63;
  const int wid = t >> 6;
  const int wr = wid >> 2, wc = wid & 3;       // 2(M) x 4(N) wave grid
  const int g4 = lane >> 4, l16 = lane & 15, l7 = lane & 7;

  const int aRow = wr * 128 + l16;             // + mh*64 + i*16
  const int bRow = wc * 64 + l16;              // + j*16
  const int col0 = ((g4) ^ l7) * 8;            // kk=0 swizzled 16B slot
  const int col1 = ((4 + g4) ^ l7) * 8;        // kk=1

  // staging: thread covers row tr (of a 64-row stripe) and 16B slot ts,
  // pre-swizzled source slot so linear LDS dest ends up swizzled.
  const int tr = t >> 3, ts = t & 7;
  const int sslot = ts ^ (tr & 7);
  const u16* srcA = Aq + (brow + tr) * (size_t)K + sslot * 8;
  const u16* srcB = Bq + (bcol + tr) * (size_t)K + sslot * 8;
  const int dst = t * 8;

  f32x4 acc0[4][4] = {};   // mh0 (rows wr*128 + 0..63)
  f32x4 acc1[4][4] = {};   // mh1 (rows wr*128 + 64..127)
  const int nK = K / BKT;

  bf16x8 aA0, aA1, aA2, aA3;   // mh0 col0
  bf16x8 aB0, aB1, aB2, aB3;   // mh0 col1
  bf16x8 aC0, aC1, aC2, aC3;   // mh1 col0
  bf16x8 aD0, aD1, aD2, aD3;   // mh1 col1
  bf16x8 bA0, bA1, bA2, bA3;   // col0
  bf16x8 bB0, bB1, bB2, bB3;   // col1

#define STA(S, R, TT) gload16(srcA + ((size_t)(R) * 64) * (size_t)K + (size_t)(TT) * BKT, \
                              &lds[S][0][(R) * 4096 + dst])
#define STB(S, R, TT) gload16(srcB + ((size_t)(R) * 64) * (size_t)K + (size_t)(TT) * BKT, \
                              &lds[S][1][(R) * 4096 + dst])
// queue order per tile: early6 = [A0,A2,B0,B1,B2,B3], late2 = [A1,A3]
#define STAGE8(S, TT) do { \
    STA(S, 0, TT); STA(S, 2, TT); STB(S, 0, TT); STB(S, 1, TT); \
    STB(S, 2, TT); STB(S, 3, TT); STA(S, 1, TT); STA(S, 3, TT); } while (0)
#define BARS() do { __builtin_amdgcn_s_barrier(); \
                    __builtin_amdgcn_sched_barrier(0); \
                    asm volatile("" ::: "memory"); } while (0)
#define VMWS(NN) do { __builtin_amdgcn_sched_barrier(0); \
                      asm volatile("s_waitcnt vmcnt(" #NN ")" ::: "memory"); } while (0)
#define RDA(P, S, MH, COL) do { \
    P##0 = *(const bf16x8*)&lds[S][0][(aRow + (MH) * 64 +  0) * 64 + (COL)]; \
    P##1 = *(const bf16x8*)&lds[S][0][(aRow + (MH) * 64 + 16) * 64 + (COL)]; \
    P##2 = *(const bf16x8*)&lds[S][0][(aRow + (MH) * 64 + 32) * 64 + (COL)]; \
    P##3 = *(const bf16x8*)&lds[S][0][(aRow + (MH) * 64 + 48) * 64 + (COL)]; } while (0)
#define RDB(P, S, COL) do { \
    P##0 = *(const bf16x8*)&lds[S][1][(bRow +  0) * 64 + (COL)]; \
    P##1 = *(const bf16x8*)&lds[S][1][(bRow + 16) * 64 + (COL)]; \
    P##2 = *(const bf16x8*)&lds[S][1][(bRow + 32) * 64 + (COL)]; \
    P##3 = *(const bf16x8*)&lds[S][1][(bRow + 48) * 64 + (COL)]; } while (0)
#define MF(ACC, A, B) do { \
    __builtin_amdgcn_s_setprio(1); \
    ACC[0][0] = __builtin_amdgcn_mfma_f32_16x16x32_bf16(A##0, B##0, ACC[0][0], 0, 0, 0); \
    ACC[0][1] = __builtin_amdgcn_mfma_f32_16x16x32_bf16(A##0, B##1, ACC[0][1], 0, 0, 0); \
    ACC[0][2] = __builtin_amdgcn_mfma_f32_16x16x32_bf16(A##0, B##2, ACC[0][2], 0, 0, 0); \
    ACC[0][3] = __builtin_amdgcn_mfma_f32_16x16x32_bf16(A##0, B##3, ACC[0][3], 0, 0, 0); \
    ACC[1][0] = __builtin_amdgcn_mfma_f32_16x16x32_bf16(A##1, B##0, ACC[1][0], 0, 0, 0); \
    ACC[1][1] = __builtin_amdgcn_mfma_f32_16x16x32_bf16(A##1, B##1, ACC[1][1], 0, 0, 0); \
    ACC[1][2] = __builtin_amdgcn_mfma_f32_16x16x32_bf16(A##1, B##2, ACC[1][2], 0, 0, 0); \
    ACC[1][3] = __builtin_amdgcn_mfma_f32_16x16x32_bf16(A##1, B##3, ACC[1][3], 0, 0, 0); \
    ACC[2][0] = __builtin_amdgcn_mfma_f32_16x16x32_bf16(A##2, B##0, ACC[2][0], 0, 0, 0); \
    ACC[2][1] = __builtin_amdgcn_mfma_f32_16x16x32_bf16(A##2, B##1, ACC[2][1], 0, 0, 0); \
    ACC[2][2] = __builtin_amdgcn_mfma_f32_16x16x32_bf16(A##2, B##2, ACC[2][2], 0, 0, 0); \
    ACC[2][3] = __builtin_amdgcn_mfma_f32_16x16x32_bf16(A##2, B##3, ACC[2][3], 0, 0, 0); \
    ACC[3][0] = __builtin_amdgcn_mfma_f32_16x16x32_bf16(A##3, B##0, ACC[3][0], 0, 0, 0); \
    ACC[3][1] = __builtin_amdgcn_mfma_f32_16x16x32_bf16(A##3, B##1, ACC[3][1], 0, 0, 0); \
    ACC[3][2] = __builtin_amdgcn_mfma_f32_16x16x32_bf16(A##3, B##2, ACC[3][2], 0, 0, 0); \
    ACC[3][3] = __builtin_amdgcn_mfma_f32_16x16x32_bf16(A##3, B##3, ACC[3][3], 0, 0, 0); \
    __builtin_amdgcn_s_setprio(0); } while (0)

  // prologue: stage tile0 -> slot0; guarantee early6; preload c1 regs.
  STAGE8(0, 0);
  VMWS(2);                        // drain early6 of tile0 (late2 in flight)
  BARS();                         // global guarantee for early6(tile0)
  RDA(aA, 0, 0, col0);
  RDB(bA, 0, col0);

  for (int kt = 0; kt < nK - 1; ++kt) {
    const int s = kt & 1, sn = s ^ 1;
    // R1: reads of early6(kt) col1 (guaranteed); c1; stage kt+1; drain late2(kt)
    BARS();
    RDA(aB, s, 0, col1);
    RDB(bB, s, col1);
    MF(acc0, aA, bA);
    STAGE8(sn, kt + 1);
    VMWS(8);                      // queue [late2_kt(2), 8 new] -> drains late2_kt
    // R2: reads of late2(kt) col0 (now guaranteed); c2
    BARS();
    RDA(aC, s, 1, col0);
    MF(acc0, aB, bB);
    // R3: reads of late2(kt) col1; c3; drain early6(kt+1)
    BARS();
    RDA(aD, s, 1, col1);
    MF(acc1, aC, bA);
    VMWS(2);                      // queue [8 of kt+1] -> drains its early6
    // R4: reads of early6(kt+1) col0 (now guaranteed); c4
    BARS();
    RDA(aA, sn, 0, col0);
    RDB(bA, sn, col0);
    MF(acc1, aD, bB);
  }

  // peeled last tile (no staging)
  {
    const int s = (nK - 1) & 1;
    BARS();
    RDA(aB, s, 0, col1);
    RDB(bB, s, col1);
    MF(acc0, aA, bA);
    VMWS(0);                      // drain late2 of last tile
    BARS();
    RDA(aC, s, 1, col0);
    MF(acc0, aB, bB);
    BARS();
    RDA(aD, s, 1, col1);
    MF(acc1, aC, bA);
    BARS();
    MF(acc1, aD, bB);
  }

  // ---------------- epilogue: scale + bias, store Y, per-row |y| max ----------------
  float swv[4], biv[4];
  size_t gcolv[4];
  #pragma unroll
  for (int j = 0; j < 4; ++j) {
    gcolv[j] = bcol + wc * 64 + j * 16 + l16;
    swv[j] = sw[gcolv[j]];
    biv[j] = bias[gcolv[j]];
  }
  #pragma unroll
  for (int mh = 0; mh < 2; ++mh) {
    #pragma unroll
    for (int i = 0; i < 4; ++i) {
      #pragma unroll
      for (int r = 0; r < 4; ++r) {
        const size_t grow = brow + (size_t)(wr * 128 + mh * 64 + i * 16 + g4 * 4 + r);
        const float sxr = sx[grow];
        float* yrow = Y + grow * (size_t)N;
        float rmax = 0.0f;
        #pragma unroll
        for (int j = 0; j < 4; ++j) {
          const float a = mh ? acc1[i][j][r] : acc0[i][j][r];
          const float y = a * (sxr * swv[j]) + biv[j];
          yrow[gcolv[j]] = y;
          rmax = fmaxf(rmax, fabsf(y));
        }
        rmax = fmaxf(rmax, __shfl_xor(rmax, 1));
        rmax = fmaxf(rmax, __shfl_xor(rmax, 2));
        rmax = fmaxf(rmax, __shfl_xor(rmax, 4));
        rmax = fmaxf(rmax, __shfl_xor(rmax, 8));
        if (l16 == 0)
          atomicMax(&rowmax[grow], __float_as_uint(rmax));
      }
    }
  }
#undef STA
#undef STB
#undef STAGE8
#undef BARS
#undef VMWS
#undef RDA
#undef RDB
#undef MF
}

// ---------------- in-place per-row output fake-quant ----------------
__global__ __launch_bounds__(256) void outquant_kernel(
    float* __restrict__ Y, const unsigned int* __restrict__ rowmax, int N)
{
  const size_t row = blockIdx.x;
  const float amax = __uint_as_float(rowmax[row]);
  const float scale = fmaxf(amax, 1e-5f) * (1.0f / 127.0f);
  float* __restrict__ p = Y + row * (size_t)N;
  const int nv = N >> 2;
  for (int i = threadIdx.x; i < nv; i += 256) {
    float4 v = ((float4*)p)[i];
    v.x = rintf(v.x / scale) * scale;
    v.y = rintf(v.y / scale) * scale;
    v.z = rintf(v.z / scale) * scale;
    v.w = rintf(v.w / scale) * scale;
    ((float4*)p)[i] = v;
  }
}

extern "C" void kernel_launch(void* const* d_in, const int* in_sizes, int n_in,
                              void* d_out, int out_size, void* d_ws, size_t ws_size,
                              hipStream_t stream)
{
  const float* x = (const float*)d_in[0];   // [B,S,D_in] fp32
  const float* wgt = (const float*)d_in[1]; // [D_out,D_in] fp32
  const float* bias = (const float*)d_in[2];// [D_out] fp32
  float* out = (float*)d_out;               // [B,S,D_out] fp32

  const int N = in_sizes[2];                // D_out
  const int K = in_sizes[1] / N;            // D_in
  const int M = in_sizes[0] / K;            // B*S

  char* ws = (char*)d_ws;
  u16* qx = (u16*)ws;               ws += (size_t)M * K * sizeof(u16);
  u16* qw = (u16*)ws;               ws += (size_t)N * K * sizeof(u16);
  float* sx = (float*)ws;           ws += (size_t)M * sizeof(float);
  float* sw = (float*)ws;           ws += (size_t)N * sizeof(float);
  unsigned int* rowmax = (unsigned int*)ws;

  hipMemsetAsync(rowmax, 0, (size_t)M * sizeof(unsigned int), stream);

  if (K == 4096) {
    quant_rows4096_kernel<<<M, 256, 0, stream>>>(x, qx, sx);
    quant_rows4096_kernel<<<N, 256, 0, stream>>>(wgt, qw, sw);
  } else {
    quant_rows_kernel<<<M, 256, 0, stream>>>(x, qx, sx, K);
    quant_rows_kernel<<<N, 256, 0, stream>>>(wgt, qw, sw, K);
  }

  const int grid = (M / BM) * (N / BN);
  gemm_bt_kernel<<<grid, 512, 0, stream>>>(qx, qw, sx, sw, bias, out, rowmax, M, N, K);

  outquant_kernel<<<M, 256, 0, stream>>>(out, rowmax, N);
}

// Round 5
// 366.356 us; speedup vs baseline: 1.0645x; 1.0645x over previous
//
#include <hip/hip_runtime.h>

typedef unsigned short u16;
typedef __attribute__((ext_vector_type(8))) short bf16x8;   // 8 bf16 = 4 VGPRs
typedef __attribute__((ext_vector_type(4))) float f32x4;

#define BM 256
#define BN 256
#define BKT 64

__device__ __forceinline__ void gload16(const void* g, void* l) {
  __builtin_amdgcn_global_load_lds(
      (const __attribute__((address_space(1))) unsigned int*)g,
      (__attribute__((address_space(3))) unsigned int*)l, 16, 0, 0);
}

// ---------------- per-row fake-quant, single-pass (K==4096) ----------------
__global__ __launch_bounds__(256) void quant_rows4096_kernel(
    const float* __restrict__ src, u16* __restrict__ q,
    float* __restrict__ scales)
{
  const size_t row = blockIdx.x;
  const float4* __restrict__ p = (const float4*)(src + row * 4096);
  const int t = threadIdx.x;
  float4 v0 = p[t];
  float4 v1 = p[t + 256];
  float4 v2 = p[t + 512];
  float4 v3 = p[t + 768];
  float m = 0.0f;
  m = fmaxf(m, fmaxf(fmaxf(fabsf(v0.x), fabsf(v0.y)), fmaxf(fabsf(v0.z), fabsf(v0.w))));
  m = fmaxf(m, fmaxf(fmaxf(fabsf(v1.x), fabsf(v1.y)), fmaxf(fabsf(v1.z), fabsf(v1.w))));
  m = fmaxf(m, fmaxf(fmaxf(fabsf(v2.x), fabsf(v2.y)), fmaxf(fabsf(v2.z), fabsf(v2.w))));
  m = fmaxf(m, fmaxf(fmaxf(fabsf(v3.x), fabsf(v3.y)), fmaxf(fabsf(v3.z), fabsf(v3.w))));
  #pragma unroll
  for (int off = 32; off > 0; off >>= 1) m = fmaxf(m, __shfl_xor(m, off));
  __shared__ float wmax[4];
  if ((t & 63) == 0) wmax[t >> 6] = m;
  __syncthreads();
  m = fmaxf(fmaxf(wmax[0], wmax[1]), fmaxf(wmax[2], wmax[3]));
  const float scale = fmaxf(m, 1e-5f) * (1.0f / 127.0f);
  if (t == 0) scales[row] = scale;
  ushort4* __restrict__ qp = (ushort4*)(q + row * 4096);
  #define QV(V, IDX) do { ushort4 o_; \
    o_.x = (u16)(__float_as_uint(rintf((V).x / scale)) >> 16); \
    o_.y = (u16)(__float_as_uint(rintf((V).y / scale)) >> 16); \
    o_.z = (u16)(__float_as_uint(rintf((V).z / scale)) >> 16); \
    o_.w = (u16)(__float_as_uint(rintf((V).w / scale)) >> 16); \
    qp[IDX] = o_; } while (0)
  QV(v0, t); QV(v1, t + 256); QV(v2, t + 512); QV(v3, t + 768);
  #undef QV
}

// generic fallback (any K multiple of 4)
__global__ __launch_bounds__(256) void quant_rows_kernel(
    const float* __restrict__ src, u16* __restrict__ q,
    float* __restrict__ scales, int K)
{
  const size_t row = blockIdx.x;
  const float* __restrict__ p = src + row * (size_t)K;
  const int t = threadIdx.x;
  const int nv = K >> 2;
  float m = 0.0f;
  for (int i = t; i < nv; i += 256) {
    float4 v = ((const float4*)p)[i];
    m = fmaxf(m, fmaxf(fmaxf(fabsf(v.x), fabsf(v.y)),
                       fmaxf(fabsf(v.z), fabsf(v.w))));
  }
  #pragma unroll
  for (int off = 32; off > 0; off >>= 1) m = fmaxf(m, __shfl_xor(m, off));
  __shared__ float wmax[4];
  if ((t & 63) == 0) wmax[t >> 6] = m;
  __syncthreads();
  m = fmaxf(fmaxf(wmax[0], wmax[1]), fmaxf(wmax[2], wmax[3]));
  const float scale = fmaxf(m, 1e-5f) * (1.0f / 127.0f);
  if (t == 0) scales[row] = scale;
  u16* __restrict__ qp = q + row * (size_t)K;
  for (int i = t; i < nv; i += 256) {
    float4 v = ((const float4*)p)[i];
    ushort4 o;
    o.x = (u16)(__float_as_uint(rintf(v.x / scale)) >> 16);
    o.y = (u16)(__float_as_uint(rintf(v.y / scale)) >> 16);
    o.z = (u16)(__float_as_uint(rintf(v.z / scale)) >> 16);
    o.w = (u16)(__float_as_uint(rintf(v.w / scale)) >> 16);
    ((ushort4*)qp)[i] = o;
  }
}

// ------- 256x256 8-wave GEMM, m201-style: 4 phases/K-tile, 2 barriers/phase -------
// Phase = { reads for THIS phase's MFMA ; stage ; [counted vmcnt] ; BAR ;
//           setprio(1) 16xMFMA setprio(0) ; BAR }.
// Ledger (per wave, FIFO): stage order per tile = e6[A0,A2,B0,B1,B2,B3], l2[A1,A3].
//   W2 end: queue = l2(kt)+8(kt+1) = 10 -> VMW(8) drains l2(kt)  (read in W3/W4)
//   W4 end: queue = 8(kt+1)            -> VMW(2) drains e6(kt+1) (read in W1/W2 next)
// Every read window's data: all-waves drain + barrier precede it. nK must be even.
__global__ __launch_bounds__(512, 2) void gemm_bt_kernel(
    const u16* __restrict__ Aq, const u16* __restrict__ Bq,
    const float* __restrict__ sx, const float* __restrict__ sw,
    const float* __restrict__ bias, float* __restrict__ Y,
    unsigned int* __restrict__ rowmax, int M, int N, int K)
{
  __shared__ u16 lds[2][2][BM * BKT];   // [slot][A/B]

  int bid = (int)blockIdx.x;
  const int nwg = (int)gridDim.x;
  if ((nwg & 7) == 0) {                 // bijective XCD swizzle
    const int cpx = nwg >> 3;
    bid = (bid & 7) * cpx + (bid >> 3);
  }
  const int ntile = N / BN;
  const size_t brow = (size_t)(bid / ntile) * BM;
  const size_t bcol = (size_t)(bid % ntile) * BN;

  const int t = threadIdx.x;
  const int lane = t & 63;
  const int wid = t >> 6;
  const int wr = wid >> 2, wc = wid & 3;       // 2(M) x 4(N) wave grid
  const int g4 = lane >> 4, l16 = lane & 15, l7 = lane & 7;

  const int aRow = wr * 128 + l16;             // + mh*64 + i*16
  const int bRow = wc * 64 + l16;              // + j*16
  const int col0 = ((g4) ^ l7) * 8;            // kk=0 swizzled 16B slot
  const int col1 = ((4 + g4) ^ l7) * 8;        // kk=1

  // staging: thread covers row tr of each 64-row stripe and 16B slot ts,
  // pre-swizzled source slot so linear LDS dest ends up swizzled.
  const int tr = t >> 3, ts = t & 7;
  const int sslot = ts ^ (tr & 7);
  const u16* srcA = Aq + (brow + tr) * (size_t)K + sslot * 8;
  const u16* srcB = Bq + (bcol + tr) * (size_t)K + sslot * 8;
  const int dst = t * 8;

  f32x4 acc0[4][4] = {};   // mh0 (rows wr*128 + 0..63)
  f32x4 acc1[4][4] = {};   // mh1 (rows wr*128 + 64..127)
  const int nK = K / BKT;

  bf16x8 aA0, aA1, aA2, aA3;   // mh0 col0
  bf16x8 aB0, aB1, aB2, aB3;   // mh0 col1
  bf16x8 aC0, aC1, aC2, aC3;   // mh1 col0
  bf16x8 aD0, aD1, aD2, aD3;   // mh1 col1
  bf16x8 bA0, bA1, bA2, bA3;   // col0
  bf16x8 bB0, bB1, bB2, bB3;   // col1

#define STA(S, R, TT) gload16(srcA + ((size_t)(R) * 64) * (size_t)K + (size_t)(TT) * BKT, \
                              &lds[S][0][(R) * 4096 + dst])
#define STB(S, R, TT) gload16(srcB + ((size_t)(R) * 64) * (size_t)K + (size_t)(TT) * BKT, \
                              &lds[S][1][(R) * 4096 + dst])
#define BARS() do { __builtin_amdgcn_s_barrier(); \
                    __builtin_amdgcn_sched_barrier(0); \
                    asm volatile("" ::: "memory"); } while (0)
#define VMWS(NN) do { __builtin_amdgcn_sched_barrier(0); \
                      asm volatile("s_waitcnt vmcnt(" #NN ")" ::: "memory"); } while (0)
#define RDA(P, S, MH, COL) do { \
    P##0 = *(const bf16x8*)&lds[S][0][(aRow + (MH) * 64 +  0) * 64 + (COL)]; \
    P##1 = *(const bf16x8*)&lds[S][0][(aRow + (MH) * 64 + 16) * 64 + (COL)]; \
    P##2 = *(const bf16x8*)&lds[S][0][(aRow + (MH) * 64 + 32) * 64 + (COL)]; \
    P##3 = *(const bf16x8*)&lds[S][0][(aRow + (MH) * 64 + 48) * 64 + (COL)]; } while (0)
#define RDB(P, S, COL) do { \
    P##0 = *(const bf16x8*)&lds[S][1][(bRow +  0) * 64 + (COL)]; \
    P##1 = *(const bf16x8*)&lds[S][1][(bRow + 16) * 64 + (COL)]; \
    P##2 = *(const bf16x8*)&lds[S][1][(bRow + 32) * 64 + (COL)]; \
    P##3 = *(const bf16x8*)&lds[S][1][(bRow + 48) * 64 + (COL)]; } while (0)
#define MF(ACC, A, B) do { \
    __builtin_amdgcn_s_setprio(1); \
    ACC[0][0] = __builtin_amdgcn_mfma_f32_16x16x32_bf16(A##0, B##0, ACC[0][0], 0, 0, 0); \
    ACC[0][1] = __builtin_amdgcn_mfma_f32_16x16x32_bf16(A##0, B##1, ACC[0][1], 0, 0, 0); \
    ACC[0][2] = __builtin_amdgcn_mfma_f32_16x16x32_bf16(A##0, B##2, ACC[0][2], 0, 0, 0); \
    ACC[0][3] = __builtin_amdgcn_mfma_f32_16x16x32_bf16(A##0, B##3, ACC[0][3], 0, 0, 0); \
    ACC[1][0] = __builtin_amdgcn_mfma_f32_16x16x32_bf16(A##1, B##0, ACC[1][0], 0, 0, 0); \
    ACC[1][1] = __builtin_amdgcn_mfma_f32_16x16x32_bf16(A##1, B##1, ACC[1][1], 0, 0, 0); \
    ACC[1][2] = __builtin_amdgcn_mfma_f32_16x16x32_bf16(A##1, B##2, ACC[1][2], 0, 0, 0); \
    ACC[1][3] = __builtin_amdgcn_mfma_f32_16x16x32_bf16(A##1, B##3, ACC[1][3], 0, 0, 0); \
    ACC[2][0] = __builtin_amdgcn_mfma_f32_16x16x32_bf16(A##2, B##0, ACC[2][0], 0, 0, 0); \
    ACC[2][1] = __builtin_amdgcn_mfma_f32_16x16x32_bf16(A##2, B##1, ACC[2][1], 0, 0, 0); \
    ACC[2][2] = __builtin_amdgcn_mfma_f32_16x16x32_bf16(A##2, B##2, ACC[2][2], 0, 0, 0); \
    ACC[2][3] = __builtin_amdgcn_mfma_f32_16x16x32_bf16(A##2, B##3, ACC[2][3], 0, 0, 0); \
    ACC[3][0] = __builtin_amdgcn_mfma_f32_16x16x32_bf16(A##3, B##0, ACC[3][0], 0, 0, 0); \
    ACC[3][1] = __builtin_amdgcn_mfma_f32_16x16x32_bf16(A##3, B##1, ACC[3][1], 0, 0, 0); \
    ACC[3][2] = __builtin_amdgcn_mfma_f32_16x16x32_bf16(A##3, B##2, ACC[3][2], 0, 0, 0); \
    ACC[3][3] = __builtin_amdgcn_mfma_f32_16x16x32_bf16(A##3, B##3, ACC[3][3], 0, 0, 0); \
    __builtin_amdgcn_s_setprio(0); } while (0)

// One K-tile in slot S, staging tile TS into slot SN.
#define BODY(S, SN, TS) do { \
    /* W1: reads e6(this) [guaranteed]; stage 4a(next) */ \
    RDA(aA, S, 0, col0); RDB(bA, S, col0); \
    STA(SN, 0, TS); STA(SN, 2, TS); STB(SN, 0, TS); STB(SN, 1, TS); \
    BARS(); MF(acc0, aA, bA); BARS(); \
    /* W2: reads e6(this) col1; stage 4b(next); drain l2(this) */ \
    RDA(aB, S, 0, col1); RDB(bB, S, col1); \
    STB(SN, 2, TS); STB(SN, 3, TS); STA(SN, 1, TS); STA(SN, 3, TS); \
    VMWS(8); \
    BARS(); MF(acc0, aB, bB); BARS(); \
    /* W3: reads l2(this) col0 [guaranteed by W2 drain+bar] */ \
    RDA(aC, S, 1, col0); \
    BARS(); MF(acc1, aC, bA); BARS(); \
    /* W4: reads l2(this) col1; drain e6(next) */ \
    RDA(aD, S, 1, col1); \
    VMWS(2); \
    BARS(); MF(acc1, aD, bB); BARS(); \
  } while (0)

  // prologue: stage tile0 -> slot0; guarantee its e6.
  STA(0, 0, 0); STA(0, 2, 0); STB(0, 0, 0); STB(0, 1, 0);
  STB(0, 2, 0); STB(0, 3, 0); STA(0, 1, 0); STA(0, 3, 0);
  VMWS(2);                        // drain e6(t0); l2(t0) in flight
  BARS();                         // global guarantee for e6(t0)

  for (int kt = 0; kt < nK - 2; kt += 2) {
    BODY(0, 1, kt + 1);
    BODY(1, 0, kt + 2);
  }
  BODY(0, 1, nK - 1);             // tile nK-2 (slot 0), stages last tile

  // peeled last tile (slot 1, no staging). entry queue: l2(last)=2.
  {
    RDA(aA, 1, 0, col0); RDB(bA, 1, col0);
    BARS(); MF(acc0, aA, bA); BARS();
    RDA(aB, 1, 0, col1); RDB(bB, 1, col1);
    VMWS(0);                      // drain l2(last)
    BARS(); MF(acc0, aB, bB); BARS();
    RDA(aC, 1, 1, col0);
    BARS(); MF(acc1, aC, bA); BARS();
    RDA(aD, 1, 1, col1);
    BARS(); MF(acc1, aD, bB);
  }

  // ---------------- epilogue: scale + bias, store Y, per-row |y| max ----------------
  float swv[4], biv[4];
  size_t gcolv[4];
  #pragma unroll
  for (int j = 0; j < 4; ++j) {
    gcolv[j] = bcol + wc * 64 + j * 16 + l16;
    swv[j] = sw[gcolv[j]];
    biv[j] = bias[gcolv[j]];
  }
  #pragma unroll
  for (int mh = 0; mh < 2; ++mh) {
    #pragma unroll
    for (int i = 0; i < 4; ++i) {
      #pragma unroll
      for (int r = 0; r < 4; ++r) {
        const size_t grow = brow + (size_t)(wr * 128 + mh * 64 + i * 16 + g4 * 4 + r);
        const float sxr = sx[grow];
        float* yrow = Y + grow * (size_t)N;
        float rmax = 0.0f;
        #pragma unroll
        for (int j = 0; j < 4; ++j) {
          const float a = mh ? acc1[i][j][r] : acc0[i][j][r];
          const float y = a * (sxr * swv[j]) + biv[j];
          yrow[gcolv[j]] = y;
          rmax = fmaxf(rmax, fabsf(y));
        }
        rmax = fmaxf(rmax, __shfl_xor(rmax, 1));
        rmax = fmaxf(rmax, __shfl_xor(rmax, 2));
        rmax = fmaxf(rmax, __shfl_xor(rmax, 4));
        rmax = fmaxf(rmax, __shfl_xor(rmax, 8));
        if (l16 == 0)
          atomicMax(&rowmax[grow], __float_as_uint(rmax));
      }
    }
  }
#undef STA
#undef STB
#undef BARS
#undef VMWS
#undef RDA
#undef RDB
#undef MF
#undef BODY
}

// ---------------- in-place per-row output fake-quant ----------------
__global__ __launch_bounds__(256) void outquant_kernel(
    float* __restrict__ Y, const unsigned int* __restrict__ rowmax, int N)
{
  const size_t row = blockIdx.x;
  const float amax = __uint_as_float(rowmax[row]);
  const float scale = fmaxf(amax, 1e-5f) * (1.0f / 127.0f);
  float* __restrict__ p = Y + row * (size_t)N;
  const int nv = N >> 2;
  for (int i = threadIdx.x; i < nv; i += 256) {
    float4 v = ((float4*)p)[i];
    v.x = rintf(v.x / scale) * scale;
    v.y = rintf(v.y / scale) * scale;
    v.z = rintf(v.z / scale) * scale;
    v.w = rintf(v.w / scale) * scale;
    ((float4*)p)[i] = v;
  }
}

extern "C" void kernel_launch(void* const* d_in, const int* in_sizes, int n_in,
                              void* d_out, int out_size, void* d_ws, size_t ws_size,
                              hipStream_t stream)
{
  const float* x = (const float*)d_in[0];   // [B,S,D_in] fp32
  const float* wgt = (const float*)d_in[1]; // [D_out,D_in] fp32
  const float* bias = (const float*)d_in[2];// [D_out] fp32
  float* out = (float*)d_out;               // [B,S,D_out] fp32

  const int N = in_sizes[2];                // D_out
  const int K = in_sizes[1] / N;            // D_in
  const int M = in_sizes[0] / K;            // B*S

  char* ws = (char*)d_ws;
  u16* qx = (u16*)ws;               ws += (size_t)M * K * sizeof(u16);
  u16* qw = (u16*)ws;               ws += (size_t)N * K * sizeof(u16);
  float* sx = (float*)ws;           ws += (size_t)M * sizeof(float);
  float* sw = (float*)ws;           ws += (size_t)N * sizeof(float);
  unsigned int* rowmax = (unsigned int*)ws;

  hipMemsetAsync(rowmax, 0, (size_t)M * sizeof(unsigned int), stream);

  if (K == 4096) {
    quant_rows4096_kernel<<<M, 256, 0, stream>>>(x, qx, sx);
    quant_rows4096_kernel<<<N, 256, 0, stream>>>(wgt, qw, sw);
  } else {
    quant_rows_kernel<<<M, 256, 0, stream>>>(x, qx, sx, K);
    quant_rows_kernel<<<N, 256, 0, stream>>>(wgt, qw, sw, K);
  }

  const int grid = (M / BM) * (N / BN);
  gemm_bt_kernel<<<grid, 512, 0, stream>>>(qx, qw, sx, sw, bias, out, rowmax, M, N, K);

  outquant_kernel<<<M, 256, 0, stream>>>(out, rowmax, N);
}

// Round 6
// 253.397 us; speedup vs baseline: 1.5390x; 1.4458x over previous
//
#include <hip/hip_runtime.h>

typedef unsigned int u32;
typedef __attribute__((ext_vector_type(4))) int i32x4;   // 16 i8 (A/B frag) or 4 i32 (C/D)

#define BM 256
#define BN 256
#define BKT 128   // K elements (i8) per K-tile: one LDS row = 128 B

__device__ __forceinline__ void gload16(const void* g, void* l) {
  __builtin_amdgcn_global_load_lds(
      (const __attribute__((address_space(1))) unsigned int*)g,
      (__attribute__((address_space(3))) unsigned int*)l, 16, 0, 0);
}

__device__ __forceinline__ u32 pack4_i8(float4 v, float scale) {
  const int a = (int)rintf(v.x / scale);
  const int b = (int)rintf(v.y / scale);
  const int c = (int)rintf(v.z / scale);
  const int d = (int)rintf(v.w / scale);
  return (u32)(a & 255) | (((u32)(b & 255)) << 8) |
         (((u32)(c & 255)) << 16) | (((u32)(d & 255)) << 24);
}

// ---------------- per-row fake-quant -> int8, single-pass (K==4096) ----------------
__global__ __launch_bounds__(256) void quant_rows4096_kernel(
    const float* __restrict__ src, u32* __restrict__ q,   // q: i8 rows packed as u32
    float* __restrict__ scales)
{
  const size_t row = blockIdx.x;
  const float4* __restrict__ p = (const float4*)(src + row * 4096);
  const int t = threadIdx.x;
  float4 v0 = p[t];
  float4 v1 = p[t + 256];
  float4 v2 = p[t + 512];
  float4 v3 = p[t + 768];
  float m = 0.0f;
  m = fmaxf(m, fmaxf(fmaxf(fabsf(v0.x), fabsf(v0.y)), fmaxf(fabsf(v0.z), fabsf(v0.w))));
  m = fmaxf(m, fmaxf(fmaxf(fabsf(v1.x), fabsf(v1.y)), fmaxf(fabsf(v1.z), fabsf(v1.w))));
  m = fmaxf(m, fmaxf(fmaxf(fabsf(v2.x), fabsf(v2.y)), fmaxf(fabsf(v2.z), fabsf(v2.w))));
  m = fmaxf(m, fmaxf(fmaxf(fabsf(v3.x), fabsf(v3.y)), fmaxf(fabsf(v3.z), fabsf(v3.w))));
  #pragma unroll
  for (int off = 32; off > 0; off >>= 1) m = fmaxf(m, __shfl_xor(m, off));
  __shared__ float wmax[4];
  if ((t & 63) == 0) wmax[t >> 6] = m;
  __syncthreads();
  m = fmaxf(fmaxf(wmax[0], wmax[1]), fmaxf(wmax[2], wmax[3]));
  const float scale = fmaxf(m, 1e-5f) * (1.0f / 127.0f);
  if (t == 0) scales[row] = scale;
  u32* __restrict__ qp = q + row * 1024;
  qp[t]       = pack4_i8(v0, scale);
  qp[t + 256] = pack4_i8(v1, scale);
  qp[t + 512] = pack4_i8(v2, scale);
  qp[t + 768] = pack4_i8(v3, scale);
}

// generic fallback (any K multiple of 4)
__global__ __launch_bounds__(256) void quant_rows_kernel(
    const float* __restrict__ src, u32* __restrict__ q,
    float* __restrict__ scales, int K)
{
  const size_t row = blockIdx.x;
  const float* __restrict__ p = src + row * (size_t)K;
  const int t = threadIdx.x;
  const int nv = K >> 2;
  float m = 0.0f;
  for (int i = t; i < nv; i += 256) {
    float4 v = ((const float4*)p)[i];
    m = fmaxf(m, fmaxf(fmaxf(fabsf(v.x), fabsf(v.y)),
                       fmaxf(fabsf(v.z), fabsf(v.w))));
  }
  #pragma unroll
  for (int off = 32; off > 0; off >>= 1) m = fmaxf(m, __shfl_xor(m, off));
  __shared__ float wmax[4];
  if ((t & 63) == 0) wmax[t >> 6] = m;
  __syncthreads();
  m = fmaxf(fmaxf(wmax[0], wmax[1]), fmaxf(wmax[2], wmax[3]));
  const float scale = fmaxf(m, 1e-5f) * (1.0f / 127.0f);
  if (t == 0) scales[row] = scale;
  u32* __restrict__ qp = q + row * ((size_t)K >> 2);
  for (int i = t; i < nv; i += 256) {
    float4 v = ((const float4*)p)[i];
    qp[i] = pack4_i8(v, scale);
  }
}

// ------- 256x256 8-wave i8 GEMM, BK=128, R5 schedule (4 windows, 2 barriers each) -------
// C = Aq(MxK) * Bq(NxK)^T, i8 inputs, i32 exact accumulate via mfma_i32_16x16x64_i8.
// LDS: 2 slots x (A 256x128B + B 256x128B) = 128 KiB. Row = 128 B = 8 x 16B slots.
// Swizzle: LDS (row, slot16) holds global (row, slot16 ^ (row&7)) — identical to R5.
// Ledger (per wave, FIFO): stage order per tile = e6[A0,A2,B0,B1,B2,B3], l2[A1,A3].
//   W2 end: queue = l2(kt)+8(kt+1) = 10 -> VMW(8) drains l2(kt)  (read in W3/W4)
//   W4 end: queue = 8(kt+1)            -> VMW(2) drains e6(kt+1) (read in W1/W2 next)
// nK = K/128 must be even.
__global__ __launch_bounds__(512, 2) void gemm_bt_kernel(
    const signed char* __restrict__ Aq, const signed char* __restrict__ Bq,
    const float* __restrict__ sx, const float* __restrict__ sw,
    const float* __restrict__ bias, float* __restrict__ Y,
    unsigned int* __restrict__ rowmax, int M, int N, int K)
{
  __shared__ signed char lds[2][2][BM * 128];   // [slot][A/B], 128 B per row

  int bid = (int)blockIdx.x;
  const int nwg = (int)gridDim.x;
  if ((nwg & 7) == 0) {                 // bijective XCD swizzle
    const int cpx = nwg >> 3;
    bid = (bid & 7) * cpx + (bid >> 3);
  }
  const int ntile = N / BN;
  const size_t brow = (size_t)(bid / ntile) * BM;
  const size_t bcol = (size_t)(bid % ntile) * BN;

  const int t = threadIdx.x;
  const int lane = t & 63;
  const int wid = t >> 6;
  const int wr = wid >> 2, wc = wid & 3;       // 2(M) x 4(N) wave grid
  const int g4 = lane >> 4, l16 = lane & 15, l7 = lane & 7;

  const int aRow = wr * 128 + l16;             // + mh*64 + i*16
  const int bRow = wc * 64 + l16;              // + j*16
  const int col0 = ((g4) ^ l7) * 16;           // kk=0 swizzled 16B slot (byte offset)
  const int col1 = ((4 + g4) ^ l7) * 16;       // kk=1

  // staging: thread covers row tr of each 64-row stripe and 16B slot ts,
  // pre-swizzled source slot so linear LDS dest ends up swizzled.
  const int tr = t >> 3, ts = t & 7;
  const int sslot = ts ^ (tr & 7);
  const signed char* srcA = Aq + (brow + tr) * (size_t)K + sslot * 16;
  const signed char* srcB = Bq + (bcol + tr) * (size_t)K + sslot * 16;
  const int dst = t * 16;                      // byte offset within 8 KiB stripe

  i32x4 acc0[4][4] = {};   // mh0 (rows wr*128 + 0..63), exact i32
  i32x4 acc1[4][4] = {};   // mh1 (rows wr*128 + 64..127)
  const int nK = K / BKT;

  i32x4 aA0, aA1, aA2, aA3;   // mh0 col0
  i32x4 aB0, aB1, aB2, aB3;   // mh0 col1
  i32x4 aC0, aC1, aC2, aC3;   // mh1 col0
  i32x4 aD0, aD1, aD2, aD3;   // mh1 col1
  i32x4 bA0, bA1, bA2, bA3;   // col0
  i32x4 bB0, bB1, bB2, bB3;   // col1

#define STA(S, R, TT) gload16(srcA + ((size_t)(R) * 64) * (size_t)K + (size_t)(TT) * BKT, \
                              &lds[S][0][(R) * 8192 + dst])
#define STB(S, R, TT) gload16(srcB + ((size_t)(R) * 64) * (size_t)K + (size_t)(TT) * BKT, \
                              &lds[S][1][(R) * 8192 + dst])
#define BARS() do { __builtin_amdgcn_s_barrier(); \
                    __builtin_amdgcn_sched_barrier(0); \
                    asm volatile("" ::: "memory"); } while (0)
#define VMWS(NN) do { __builtin_amdgcn_sched_barrier(0); \
                      asm volatile("s_waitcnt vmcnt(" #NN ")" ::: "memory"); } while (0)
#define RDA(P, S, MH, COL) do { \
    P##0 = *(const i32x4*)&lds[S][0][(aRow + (MH) * 64 +  0) * 128 + (COL)]; \
    P##1 = *(const i32x4*)&lds[S][0][(aRow + (MH) * 64 + 16) * 128 + (COL)]; \
    P##2 = *(const i32x4*)&lds[S][0][(aRow + (MH) * 64 + 32) * 128 + (COL)]; \
    P##3 = *(const i32x4*)&lds[S][0][(aRow + (MH) * 64 + 48) * 128 + (COL)]; } while (0)
#define RDB(P, S, COL) do { \
    P##0 = *(const i32x4*)&lds[S][1][(bRow +  0) * 128 + (COL)]; \
    P##1 = *(const i32x4*)&lds[S][1][(bRow + 16) * 128 + (COL)]; \
    P##2 = *(const i32x4*)&lds[S][1][(bRow + 32) * 128 + (COL)]; \
    P##3 = *(const i32x4*)&lds[S][1][(bRow + 48) * 128 + (COL)]; } while (0)
#define MF(ACC, A, B) do { \
    __builtin_amdgcn_s_setprio(1); \
    ACC[0][0] = __builtin_amdgcn_mfma_i32_16x16x64_i8(A##0, B##0, ACC[0][0], 0, 0, 0); \
    ACC[0][1] = __builtin_amdgcn_mfma_i32_16x16x64_i8(A##0, B##1, ACC[0][1], 0, 0, 0); \
    ACC[0][2] = __builtin_amdgcn_mfma_i32_16x16x64_i8(A##0, B##2, ACC[0][2], 0, 0, 0); \
    ACC[0][3] = __builtin_amdgcn_mfma_i32_16x16x64_i8(A##0, B##3, ACC[0][3], 0, 0, 0); \
    ACC[1][0] = __builtin_amdgcn_mfma_i32_16x16x64_i8(A##1, B##0, ACC[1][0], 0, 0, 0); \
    ACC[1][1] = __builtin_amdgcn_mfma_i32_16x16x64_i8(A##1, B##1, ACC[1][1], 0, 0, 0); \
    ACC[1][2] = __builtin_amdgcn_mfma_i32_16x16x64_i8(A##1, B##2, ACC[1][2], 0, 0, 0); \
    ACC[1][3] = __builtin_amdgcn_mfma_i32_16x16x64_i8(A##1, B##3, ACC[1][3], 0, 0, 0); \
    ACC[2][0] = __builtin_amdgcn_mfma_i32_16x16x64_i8(A##2, B##0, ACC[2][0], 0, 0, 0); \
    ACC[2][1] = __builtin_amdgcn_mfma_i32_16x16x64_i8(A##2, B##1, ACC[2][1], 0, 0, 0); \
    ACC[2][2] = __builtin_amdgcn_mfma_i32_16x16x64_i8(A##2, B##2, ACC[2][2], 0, 0, 0); \
    ACC[2][3] = __builtin_amdgcn_mfma_i32_16x16x64_i8(A##2, B##3, ACC[2][3], 0, 0, 0); \
    ACC[3][0] = __builtin_amdgcn_mfma_i32_16x16x64_i8(A##3, B##0, ACC[3][0], 0, 0, 0); \
    ACC[3][1] = __builtin_amdgcn_mfma_i32_16x16x64_i8(A##3, B##1, ACC[3][1], 0, 0, 0); \
    ACC[3][2] = __builtin_amdgcn_mfma_i32_16x16x64_i8(A##3, B##2, ACC[3][2], 0, 0, 0); \
    ACC[3][3] = __builtin_amdgcn_mfma_i32_16x16x64_i8(A##3, B##3, ACC[3][3], 0, 0, 0); \
    __builtin_amdgcn_s_setprio(0); } while (0)

// One K-tile in slot S, staging tile TS into slot SN.
#define BODY(S, SN, TS) do { \
    /* W1: reads e6(this) [guaranteed]; stage 4a(next) */ \
    RDA(aA, S, 0, col0); RDB(bA, S, col0); \
    STA(SN, 0, TS); STA(SN, 2, TS); STB(SN, 0, TS); STB(SN, 1, TS); \
    BARS(); MF(acc0, aA, bA); BARS(); \
    /* W2: reads e6(this) col1; stage 4b(next); drain l2(this) */ \
    RDA(aB, S, 0, col1); RDB(bB, S, col1); \
    STB(SN, 2, TS); STB(SN, 3, TS); STA(SN, 1, TS); STA(SN, 3, TS); \
    VMWS(8); \
    BARS(); MF(acc0, aB, bB); BARS(); \
    /* W3: reads l2(this) col0 [guaranteed by W2 drain+bar] */ \
    RDA(aC, S, 1, col0); \
    BARS(); MF(acc1, aC, bA); BARS(); \
    /* W4: reads l2(this) col1; drain e6(next) */ \
    RDA(aD, S, 1, col1); \
    VMWS(2); \
    BARS(); MF(acc1, aD, bB); BARS(); \
  } while (0)

  // prologue: stage tile0 -> slot0; guarantee its e6.
  STA(0, 0, 0); STA(0, 2, 0); STB(0, 0, 0); STB(0, 1, 0);
  STB(0, 2, 0); STB(0, 3, 0); STA(0, 1, 0); STA(0, 3, 0);
  VMWS(2);                        // drain e6(t0); l2(t0) in flight
  BARS();                         // global guarantee for e6(t0)

  for (int kt = 0; kt < nK - 2; kt += 2) {
    BODY(0, 1, kt + 1);
    BODY(1, 0, kt + 2);
  }
  BODY(0, 1, nK - 1);             // tile nK-2 (slot 0), stages last tile

  // peeled last tile (slot 1, no staging). entry queue: l2(last)=2.
  {
    RDA(aA, 1, 0, col0); RDB(bA, 1, col0);
    BARS(); MF(acc0, aA, bA); BARS();
    RDA(aB, 1, 0, col1); RDB(bB, 1, col1);
    VMWS(0);                      // drain l2(last)
    BARS(); MF(acc0, aB, bB); BARS();
    RDA(aC, 1, 1, col0);
    BARS(); MF(acc1, aC, bA); BARS();
    RDA(aD, 1, 1, col1);
    BARS(); MF(acc1, aD, bB);
  }

  // ---------------- epilogue: scale + bias, store Y, per-row |y| max ----------------
  float swv[4], biv[4];
  size_t gcolv[4];
  #pragma unroll
  for (int j = 0; j < 4; ++j) {
    gcolv[j] = bcol + wc * 64 + j * 16 + l16;
    swv[j] = sw[gcolv[j]];
    biv[j] = bias[gcolv[j]];
  }
  #pragma unroll
  for (int mh = 0; mh < 2; ++mh) {
    #pragma unroll
    for (int i = 0; i < 4; ++i) {
      #pragma unroll
      for (int r = 0; r < 4; ++r) {
        const size_t grow = brow + (size_t)(wr * 128 + mh * 64 + i * 16 + g4 * 4 + r);
        const float sxr = sx[grow];
        float* yrow = Y + grow * (size_t)N;
        float rmax = 0.0f;
        #pragma unroll
        for (int j = 0; j < 4; ++j) {
          const int av = mh ? acc1[i][j][r] : acc0[i][j][r];
          const float y = (float)av * (sxr * swv[j]) + biv[j];
          yrow[gcolv[j]] = y;
          rmax = fmaxf(rmax, fabsf(y));
        }
        rmax = fmaxf(rmax, __shfl_xor(rmax, 1));
        rmax = fmaxf(rmax, __shfl_xor(rmax, 2));
        rmax = fmaxf(rmax, __shfl_xor(rmax, 4));
        rmax = fmaxf(rmax, __shfl_xor(rmax, 8));
        if (l16 == 0)
          atomicMax(&rowmax[grow], __float_as_uint(rmax));
      }
    }
  }
#undef STA
#undef STB
#undef BARS
#undef VMWS
#undef RDA
#undef RDB
#undef MF
#undef BODY
}

// ---------------- in-place per-row output fake-quant ----------------
__global__ __launch_bounds__(256) void outquant_kernel(
    float* __restrict__ Y, const unsigned int* __restrict__ rowmax, int N)
{
  const size_t row = blockIdx.x;
  const float amax = __uint_as_float(rowmax[row]);
  const float scale = fmaxf(amax, 1e-5f) * (1.0f / 127.0f);
  float* __restrict__ p = Y + row * (size_t)N;
  const int nv = N >> 2;
  for (int i = threadIdx.x; i < nv; i += 256) {
    float4 v = ((float4*)p)[i];
    v.x = rintf(v.x / scale) * scale;
    v.y = rintf(v.y / scale) * scale;
    v.z = rintf(v.z / scale) * scale;
    v.w = rintf(v.w / scale) * scale;
    ((float4*)p)[i] = v;
  }
}

extern "C" void kernel_launch(void* const* d_in, const int* in_sizes, int n_in,
                              void* d_out, int out_size, void* d_ws, size_t ws_size,
                              hipStream_t stream)
{
  const float* x = (const float*)d_in[0];   // [B,S,D_in] fp32
  const float* wgt = (const float*)d_in[1]; // [D_out,D_in] fp32
  const float* bias = (const float*)d_in[2];// [D_out] fp32
  float* out = (float*)d_out;               // [B,S,D_out] fp32

  const int N = in_sizes[2];                // D_out
  const int K = in_sizes[1] / N;            // D_in
  const int M = in_sizes[0] / K;            // B*S

  char* ws = (char*)d_ws;
  signed char* qx = (signed char*)ws;  ws += (size_t)M * K;         // i8
  signed char* qw = (signed char*)ws;  ws += (size_t)N * K;         // i8
  float* sx = (float*)ws;              ws += (size_t)M * sizeof(float);
  float* sw = (float*)ws;              ws += (size_t)N * sizeof(float);
  unsigned int* rowmax = (unsigned int*)ws;

  hipMemsetAsync(rowmax, 0, (size_t)M * sizeof(unsigned int), stream);

  if (K == 4096) {
    quant_rows4096_kernel<<<M, 256, 0, stream>>>(x, (u32*)qx, sx);
    quant_rows4096_kernel<<<N, 256, 0, stream>>>(wgt, (u32*)qw, sw);
  } else {
    quant_rows_kernel<<<M, 256, 0, stream>>>(x, (u32*)qx, sx, K);
    quant_rows_kernel<<<N, 256, 0, stream>>>(wgt, (u32*)qw, sw, K);
  }

  const int grid = (M / BM) * (N / BN);
  gemm_bt_kernel<<<grid, 512, 0, stream>>>(qx, qw, sx, sw, bias, out, rowmax, M, N, K);

  outquant_kernel<<<M, 256, 0, stream>>>(out, rowmax, N);
}

// Round 7
// 250.526 us; speedup vs baseline: 1.5566x; 1.0115x over previous
//
#include <hip/hip_runtime.h>

typedef unsigned int u32;
typedef __attribute__((ext_vector_type(4))) int i32x4;   // 16 i8 (A/B frag) or 4 i32 (C/D)

#define BM 256
#define BN 256
#define BKT 128   // K elements (i8) per K-tile: one LDS row = 128 B

__device__ __forceinline__ void gload16(const void* g, void* l) {
  __builtin_amdgcn_global_load_lds(
      (const __attribute__((address_space(1))) unsigned int*)g,
      (__attribute__((address_space(3))) unsigned int*)l, 16, 0, 0);
}

__device__ __forceinline__ u32 pack4_i8(float4 v, float scale) {
  const int a = (int)rintf(v.x / scale);
  const int b = (int)rintf(v.y / scale);
  const int c = (int)rintf(v.z / scale);
  const int d = (int)rintf(v.w / scale);
  return (u32)(a & 255) | (((u32)(b & 255)) << 8) |
         (((u32)(c & 255)) << 16) | (((u32)(d & 255)) << 24);
}

// ---------------- per-row fake-quant -> int8, single-pass (K==4096) ----------------
__global__ __launch_bounds__(256) void quant_rows4096_kernel(
    const float* __restrict__ src, u32* __restrict__ q,   // q: i8 rows packed as u32
    float* __restrict__ scales)
{
  const size_t row = blockIdx.x;
  const float4* __restrict__ p = (const float4*)(src + row * 4096);
  const int t = threadIdx.x;
  float4 v0 = p[t];
  float4 v1 = p[t + 256];
  float4 v2 = p[t + 512];
  float4 v3 = p[t + 768];
  float m = 0.0f;
  m = fmaxf(m, fmaxf(fmaxf(fabsf(v0.x), fabsf(v0.y)), fmaxf(fabsf(v0.z), fabsf(v0.w))));
  m = fmaxf(m, fmaxf(fmaxf(fabsf(v1.x), fabsf(v1.y)), fmaxf(fabsf(v1.z), fabsf(v1.w))));
  m = fmaxf(m, fmaxf(fmaxf(fabsf(v2.x), fabsf(v2.y)), fmaxf(fabsf(v2.z), fabsf(v2.w))));
  m = fmaxf(m, fmaxf(fmaxf(fabsf(v3.x), fabsf(v3.y)), fmaxf(fabsf(v3.z), fabsf(v3.w))));
  #pragma unroll
  for (int off = 32; off > 0; off >>= 1) m = fmaxf(m, __shfl_xor(m, off));
  __shared__ float wmax[4];
  if ((t & 63) == 0) wmax[t >> 6] = m;
  __syncthreads();
  m = fmaxf(fmaxf(wmax[0], wmax[1]), fmaxf(wmax[2], wmax[3]));
  const float scale = fmaxf(m, 1e-5f) * (1.0f / 127.0f);
  if (t == 0) scales[row] = scale;
  u32* __restrict__ qp = q + row * 1024;
  qp[t]       = pack4_i8(v0, scale);
  qp[t + 256] = pack4_i8(v1, scale);
  qp[t + 512] = pack4_i8(v2, scale);
  qp[t + 768] = pack4_i8(v3, scale);
}

// generic fallback (any K multiple of 4)
__global__ __launch_bounds__(256) void quant_rows_kernel(
    const float* __restrict__ src, u32* __restrict__ q,
    float* __restrict__ scales, int K)
{
  const size_t row = blockIdx.x;
  const float* __restrict__ p = src + row * (size_t)K;
  const int t = threadIdx.x;
  const int nv = K >> 2;
  float m = 0.0f;
  for (int i = t; i < nv; i += 256) {
    float4 v = ((const float4*)p)[i];
    m = fmaxf(m, fmaxf(fmaxf(fabsf(v.x), fabsf(v.y)),
                       fmaxf(fabsf(v.z), fabsf(v.w))));
  }
  #pragma unroll
  for (int off = 32; off > 0; off >>= 1) m = fmaxf(m, __shfl_xor(m, off));
  __shared__ float wmax[4];
  if ((t & 63) == 0) wmax[t >> 6] = m;
  __syncthreads();
  m = fmaxf(fmaxf(wmax[0], wmax[1]), fmaxf(wmax[2], wmax[3]));
  const float scale = fmaxf(m, 1e-5f) * (1.0f / 127.0f);
  if (t == 0) scales[row] = scale;
  u32* __restrict__ qp = q + row * ((size_t)K >> 2);
  for (int i = t; i < nv; i += 256) {
    float4 v = ((const float4*)p)[i];
    qp[i] = pack4_i8(v, scale);
  }
}

// ------- 256x256 8-wave i8 GEMM, BK=128, R6 schedule WITHOUT sched_barrier pins -------
// C = Aq(MxK) * Bq(NxK)^T, i8 inputs, i32 exact accumulate via mfma_i32_16x16x64_i8.
// LDS: 2 slots x (A 256x128B + B 256x128B) = 128 KiB. Row = 128 B = 8 x 16B slots.
// Swizzle: LDS (row, slot16) holds global (row, slot16 ^ (row&7)).
// Ledger (per wave, FIFO): stage order per tile = e6[A0,A2,B0,B1,B2,B3], l2[A1,A3].
//   W2 end: queue = l2(kt)+8(kt+1) = 10 -> VMW(8) drains l2(kt)  (read in W3/W4)
//   W4 end: queue = 8(kt+1)            -> VMW(2) drains e6(kt+1) (read in W1/W2 next)
// Memory ordering via "memory"-clobber fences around s_barrier / vmcnt asm only;
// NO sched_barrier(0) (m141: order-pinning defeats the scheduler, -40%).
__global__ __launch_bounds__(512, 2) void gemm_bt_kernel(
    const signed char* __restrict__ Aq, const signed char* __restrict__ Bq,
    const float* __restrict__ sx, const float* __restrict__ sw,
    const float* __restrict__ bias, float* __restrict__ Y,
    unsigned int* __restrict__ rowmax, int M, int N, int K)
{
  __shared__ signed char lds[2][2][BM * 128];   // [slot][A/B], 128 B per row

  int bid = (int)blockIdx.x;
  const int nwg = (int)gridDim.x;
  if ((nwg & 7) == 0) {                 // bijective XCD swizzle
    const int cpx = nwg >> 3;
    bid = (bid & 7) * cpx + (bid >> 3);
  }
  const int ntile = N / BN;
  const size_t brow = (size_t)(bid / ntile) * BM;
  const size_t bcol = (size_t)(bid % ntile) * BN;

  const int t = threadIdx.x;
  const int lane = t & 63;
  const int wid = t >> 6;
  const int wr = wid >> 2, wc = wid & 3;       // 2(M) x 4(N) wave grid
  const int g4 = lane >> 4, l16 = lane & 15, l7 = lane & 7;

  const int aRow = wr * 128 + l16;             // + mh*64 + i*16
  const int bRow = wc * 64 + l16;              // + j*16
  const int col0 = ((g4) ^ l7) * 16;           // kk=0 swizzled 16B slot (byte offset)
  const int col1 = ((4 + g4) ^ l7) * 16;       // kk=1

  // staging: thread covers row tr of each 64-row stripe and 16B slot ts,
  // pre-swizzled source slot so linear LDS dest ends up swizzled.
  const int tr = t >> 3, ts = t & 7;
  const int sslot = ts ^ (tr & 7);
  const signed char* srcA = Aq + (brow + tr) * (size_t)K + sslot * 16;
  const signed char* srcB = Bq + (bcol + tr) * (size_t)K + sslot * 16;
  const int dst = t * 16;                      // byte offset within 8 KiB stripe

  i32x4 acc0[4][4] = {};   // mh0 (rows wr*128 + 0..63), exact i32
  i32x4 acc1[4][4] = {};   // mh1 (rows wr*128 + 64..127)
  const int nK = K / BKT;

  i32x4 aA0, aA1, aA2, aA3;   // mh0 col0
  i32x4 aB0, aB1, aB2, aB3;   // mh0 col1
  i32x4 aC0, aC1, aC2, aC3;   // mh1 col0
  i32x4 aD0, aD1, aD2, aD3;   // mh1 col1
  i32x4 bA0, bA1, bA2, bA3;   // col0
  i32x4 bB0, bB1, bB2, bB3;   // col1

#define STA(S, R, TT) gload16(srcA + ((size_t)(R) * 64) * (size_t)K + (size_t)(TT) * BKT, \
                              &lds[S][0][(R) * 8192 + dst])
#define STB(S, R, TT) gload16(srcB + ((size_t)(R) * 64) * (size_t)K + (size_t)(TT) * BKT, \
                              &lds[S][1][(R) * 8192 + dst])
#define BARS() do { asm volatile("" ::: "memory"); \
                    __builtin_amdgcn_s_barrier(); \
                    asm volatile("" ::: "memory"); } while (0)
#define VMWS(NN) asm volatile("s_waitcnt vmcnt(" #NN ")" ::: "memory")
#define RDA(P, S, MH, COL) do { \
    P##0 = *(const i32x4*)&lds[S][0][(aRow + (MH) * 64 +  0) * 128 + (COL)]; \
    P##1 = *(const i32x4*)&lds[S][0][(aRow + (MH) * 64 + 16) * 128 + (COL)]; \
    P##2 = *(const i32x4*)&lds[S][0][(aRow + (MH) * 64 + 32) * 128 + (COL)]; \
    P##3 = *(const i32x4*)&lds[S][0][(aRow + (MH) * 64 + 48) * 128 + (COL)]; } while (0)
#define RDB(P, S, COL) do { \
    P##0 = *(const i32x4*)&lds[S][1][(bRow +  0) * 128 + (COL)]; \
    P##1 = *(const i32x4*)&lds[S][1][(bRow + 16) * 128 + (COL)]; \
    P##2 = *(const i32x4*)&lds[S][1][(bRow + 32) * 128 + (COL)]; \
    P##3 = *(const i32x4*)&lds[S][1][(bRow + 48) * 128 + (COL)]; } while (0)
#define MF(ACC, A, B) do { \
    __builtin_amdgcn_s_setprio(1); \
    ACC[0][0] = __builtin_amdgcn_mfma_i32_16x16x64_i8(A##0, B##0, ACC[0][0], 0, 0, 0); \
    ACC[0][1] = __builtin_amdgcn_mfma_i32_16x16x64_i8(A##0, B##1, ACC[0][1], 0, 0, 0); \
    ACC[0][2] = __builtin_amdgcn_mfma_i32_16x16x64_i8(A##0, B##2, ACC[0][2], 0, 0, 0); \
    ACC[0][3] = __builtin_amdgcn_mfma_i32_16x16x64_i8(A##0, B##3, ACC[0][3], 0, 0, 0); \
    ACC[1][0] = __builtin_amdgcn_mfma_i32_16x16x64_i8(A##1, B##0, ACC[1][0], 0, 0, 0); \
    ACC[1][1] = __builtin_amdgcn_mfma_i32_16x16x64_i8(A##1, B##1, ACC[1][1], 0, 0, 0); \
    ACC[1][2] = __builtin_amdgcn_mfma_i32_16x16x64_i8(A##1, B##2, ACC[1][2], 0, 0, 0); \
    ACC[1][3] = __builtin_amdgcn_mfma_i32_16x16x64_i8(A##1, B##3, ACC[1][3], 0, 0, 0); \
    ACC[2][0] = __builtin_amdgcn_mfma_i32_16x16x64_i8(A##2, B##0, ACC[2][0], 0, 0, 0); \
    ACC[2][1] = __builtin_amdgcn_mfma_i32_16x16x64_i8(A##2, B##1, ACC[2][1], 0, 0, 0); \
    ACC[2][2] = __builtin_amdgcn_mfma_i32_16x16x64_i8(A##2, B##2, ACC[2][2], 0, 0, 0); \
    ACC[2][3] = __builtin_amdgcn_mfma_i32_16x16x64_i8(A##2, B##3, ACC[2][3], 0, 0, 0); \
    ACC[3][0] = __builtin_amdgcn_mfma_i32_16x16x64_i8(A##3, B##0, ACC[3][0], 0, 0, 0); \
    ACC[3][1] = __builtin_amdgcn_mfma_i32_16x16x64_i8(A##3, B##1, ACC[3][1], 0, 0, 0); \
    ACC[3][2] = __builtin_amdgcn_mfma_i32_16x16x64_i8(A##3, B##2, ACC[3][2], 0, 0, 0); \
    ACC[3][3] = __builtin_amdgcn_mfma_i32_16x16x64_i8(A##3, B##3, ACC[3][3], 0, 0, 0); \
    __builtin_amdgcn_s_setprio(0); } while (0)

// One K-tile in slot S, staging tile TS into slot SN.
#define BODY(S, SN, TS) do { \
    /* W1: reads e6(this) [guaranteed]; stage 4a(next) */ \
    RDA(aA, S, 0, col0); RDB(bA, S, col0); \
    STA(SN, 0, TS); STA(SN, 2, TS); STB(SN, 0, TS); STB(SN, 1, TS); \
    BARS(); MF(acc0, aA, bA); BARS(); \
    /* W2: reads e6(this) col1; stage 4b(next); drain l2(this) */ \
    RDA(aB, S, 0, col1); RDB(bB, S, col1); \
    STB(SN, 2, TS); STB(SN, 3, TS); STA(SN, 1, TS); STA(SN, 3, TS); \
    VMWS(8); \
    BARS(); MF(acc0, aB, bB); BARS(); \
    /* W3: reads l2(this) col0 [guaranteed by W2 drain+bar] */ \
    RDA(aC, S, 1, col0); \
    BARS(); MF(acc1, aC, bA); BARS(); \
    /* W4: reads l2(this) col1; drain e6(next) */ \
    RDA(aD, S, 1, col1); \
    VMWS(2); \
    BARS(); MF(acc1, aD, bB); BARS(); \
  } while (0)

  // prologue: stage tile0 -> slot0; guarantee its e6.
  STA(0, 0, 0); STA(0, 2, 0); STB(0, 0, 0); STB(0, 1, 0);
  STB(0, 2, 0); STB(0, 3, 0); STA(0, 1, 0); STA(0, 3, 0);
  VMWS(2);                        // drain e6(t0); l2(t0) in flight
  BARS();                         // global guarantee for e6(t0)

  for (int kt = 0; kt < nK - 2; kt += 2) {
    BODY(0, 1, kt + 1);
    BODY(1, 0, kt + 2);
  }
  BODY(0, 1, nK - 1);             // tile nK-2 (slot 0), stages last tile

  // peeled last tile (slot 1, no staging). entry queue: l2(last)=2.
  {
    RDA(aA, 1, 0, col0); RDB(bA, 1, col0);
    BARS(); MF(acc0, aA, bA); BARS();
    RDA(aB, 1, 0, col1); RDB(bB, 1, col1);
    VMWS(0);                      // drain l2(last)
    BARS(); MF(acc0, aB, bB); BARS();
    RDA(aC, 1, 1, col0);
    BARS(); MF(acc1, aC, bA); BARS();
    RDA(aD, 1, 1, col1);
    BARS(); MF(acc1, aD, bB);
  }

  // ---------------- epilogue: scale + bias, store Y, per-row |y| max ----------------
  float swv[4], biv[4];
  size_t gcolv[4];
  #pragma unroll
  for (int j = 0; j < 4; ++j) {
    gcolv[j] = bcol + wc * 64 + j * 16 + l16;
    swv[j] = sw[gcolv[j]];
    biv[j] = bias[gcolv[j]];
  }
  #pragma unroll
  for (int mh = 0; mh < 2; ++mh) {
    #pragma unroll
    for (int i = 0; i < 4; ++i) {
      #pragma unroll
      for (int r = 0; r < 4; ++r) {
        const size_t grow = brow + (size_t)(wr * 128 + mh * 64 + i * 16 + g4 * 4 + r);
        const float sxr = sx[grow];
        float* yrow = Y + grow * (size_t)N;
        float rmax = 0.0f;
        #pragma unroll
        for (int j = 0; j < 4; ++j) {
          const int av = mh ? acc1[i][j][r] : acc0[i][j][r];
          const float y = (float)av * (sxr * swv[j]) + biv[j];
          yrow[gcolv[j]] = y;
          rmax = fmaxf(rmax, fabsf(y));
        }
        rmax = fmaxf(rmax, __shfl_xor(rmax, 1));
        rmax = fmaxf(rmax, __shfl_xor(rmax, 2));
        rmax = fmaxf(rmax, __shfl_xor(rmax, 4));
        rmax = fmaxf(rmax, __shfl_xor(rmax, 8));
        if (l16 == 0)
          atomicMax(&rowmax[grow], __float_as_uint(rmax));
      }
    }
  }
#undef STA
#undef STB
#undef BARS
#undef VMWS
#undef RDA
#undef RDB
#undef MF
#undef BODY
}

// ---------------- in-place per-row output fake-quant ----------------
__global__ __launch_bounds__(256) void outquant_kernel(
    float* __restrict__ Y, const unsigned int* __restrict__ rowmax, int N)
{
  const size_t row = blockIdx.x;
  const float amax = __uint_as_float(rowmax[row]);
  const float scale = fmaxf(amax, 1e-5f) * (1.0f / 127.0f);
  float* __restrict__ p = Y + row * (size_t)N;
  const int nv = N >> 2;
  for (int i = threadIdx.x; i < nv; i += 256) {
    float4 v = ((float4*)p)[i];
    v.x = rintf(v.x / scale) * scale;
    v.y = rintf(v.y / scale) * scale;
    v.z = rintf(v.z / scale) * scale;
    v.w = rintf(v.w / scale) * scale;
    ((float4*)p)[i] = v;
  }
}

extern "C" void kernel_launch(void* const* d_in, const int* in_sizes, int n_in,
                              void* d_out, int out_size, void* d_ws, size_t ws_size,
                              hipStream_t stream)
{
  const float* x = (const float*)d_in[0];   // [B,S,D_in] fp32
  const float* wgt = (const float*)d_in[1]; // [D_out,D_in] fp32
  const float* bias = (const float*)d_in[2];// [D_out] fp32
  float* out = (float*)d_out;               // [B,S,D_out] fp32

  const int N = in_sizes[2];                // D_out
  const int K = in_sizes[1] / N;            // D_in
  const int M = in_sizes[0] / K;            // B*S

  char* ws = (char*)d_ws;
  signed char* qx = (signed char*)ws;  ws += (size_t)M * K;         // i8
  signed char* qw = (signed char*)ws;  ws += (size_t)N * K;         // i8
  float* sx = (float*)ws;              ws += (size_t)M * sizeof(float);
  float* sw = (float*)ws;              ws += (size_t)N * sizeof(float);
  unsigned int* rowmax = (unsigned int*)ws;

  hipMemsetAsync(rowmax, 0, (size_t)M * sizeof(unsigned int), stream);

  if (K == 4096) {
    quant_rows4096_kernel<<<M, 256, 0, stream>>>(x, (u32*)qx, sx);
    quant_rows4096_kernel<<<N, 256, 0, stream>>>(wgt, (u32*)qw, sw);
  } else {
    quant_rows_kernel<<<M, 256, 0, stream>>>(x, (u32*)qx, sx, K);
    quant_rows_kernel<<<N, 256, 0, stream>>>(wgt, (u32*)qw, sw, K);
  }

  const int grid = (M / BM) * (N / BN);
  gemm_bt_kernel<<<grid, 512, 0, stream>>>(qx, qw, sx, sw, bias, out, rowmax, M, N, K);

  outquant_kernel<<<M, 256, 0, stream>>>(out, rowmax, N);
}